// Round 5
// baseline (220.641 us; speedup 1.0000x reference)
//
#include <hip/hip_runtime.h>
#include <hip/hip_bf16.h>
#include <cstdint>
#include <cmath>

#define SEQ 2048
#define NH 16
#define DM 1024
#define BATCH 2

typedef short bf16x8 __attribute__((ext_vector_type(8)));
typedef float f32x4 __attribute__((ext_vector_type(4)));
typedef const void __attribute__((address_space(1)))* gas_t;
typedef void __attribute__((address_space(3)))* las_t;

#if __has_builtin(__builtin_amdgcn_exp2f)
#define EXP2(x) __builtin_amdgcn_exp2f(x)
#else
#define EXP2(x) __expf((x) * 0.6931471805599453f)
#endif

// Q prescale: (1/sqrt(64)) * log2(e) so scores are already in log2 domain
#define QSCALE 0.18033688011112042f

static __device__ __forceinline__ unsigned short f2bf(float f) {
    union { __hip_bfloat16 h; unsigned short u; } cv;
    cv.h = __float2bfloat16(f);
    return cv.u;
}
static __device__ __forceinline__ float bf2f(unsigned short u) {
    union { unsigned short u; __hip_bfloat16 h; } cv;
    cv.u = u;
    return __bfloat162float(cv.h);
}

static __device__ __forceinline__ void gload_lds16(const void* g, void* l) {
    __builtin_amdgcn_global_load_lds(
        reinterpret_cast<gas_t>(reinterpret_cast<uintptr_t>(g)),
        reinterpret_cast<las_t>(reinterpret_cast<uintptr_t>(l)),
        16, 0, 0);
}

// ---------------- fp32 -> bf16 convert, all 5 tensors in one launch ----------
__global__ __launch_bounds__(256) void cvt_all(
    const float* __restrict__ x,  const float* __restrict__ wq,
    const float* __restrict__ wk, const float* __restrict__ wv,
    const float* __restrict__ wo,
    unsigned short* __restrict__ xb, unsigned short* __restrict__ wqkv,
    unsigned short* __restrict__ wob) {
    int blk = blockIdx.x;
    const float* src; unsigned short* dst; int base;
    if (blk < 4096)      { src = x;  dst = xb;              base = blk; }
    else if (blk < 5120) { src = wq; dst = wqkv;            base = blk - 4096; }
    else if (blk < 6144) { src = wk; dst = wqkv + 1048576;  base = blk - 5120; }
    else if (blk < 7168) { src = wv; dst = wqkv + 2097152;  base = blk - 6144; }
    else                 { src = wo; dst = wob;             base = blk - 7168; }
    int i = base * 256 + threadIdx.x;
    float4 v = reinterpret_cast<const float4*>(src)[i];
    ushort4 o;
    o.x = f2bf(v.x); o.y = f2bf(v.y); o.z = f2bf(v.z); o.w = f2bf(v.w);
    reinterpret_cast<ushort4*>(dst)[i] = o;
}

// ---------------- bf16 GEMM: C[M][N] = A[M][K] * B[N][K]^T ----------------
template<int OUT_BF16>
__global__ __launch_bounds__(256) void gemm_bt(
    const unsigned short* __restrict__ A,
    const unsigned short* __restrict__ B,
    void* __restrict__ C, int M, int N, int K) {
    __shared__ unsigned short As[128 * 32];
    __shared__ unsigned short Bs[128 * 32];
    const int tid = threadIdx.x;
    const int lane = tid & 63, wid = tid >> 6;
    const int wr = wid >> 1, wc = wid & 1;
    const int ln15 = lane & 15, kq = lane >> 4;
    const int bm = blockIdx.y, bn = blockIdx.x;

    f32x4 acc[4][4] = {};
    const int nk = K >> 5;
    for (int kt = 0; kt < nk; ++kt) {
        #pragma unroll
        for (int i = 0; i < 2; ++i) {
            int c = i * 256 + tid;
            int row = c >> 2, k8 = (c & 3) << 3;
            size_t gofsA = (size_t)(bm * 128 + row) * K + kt * 32 + k8;
            size_t gofsB = (size_t)(bn * 128 + row) * K + kt * 32 + k8;
            unsigned ldsoff = (unsigned)(i * 256 + wid * 64) * 16;  // wave-uniform
            gload_lds16(A + gofsA, (char*)As + ldsoff);
            gload_lds16(B + gofsB, (char*)Bs + ldsoff);
        }
        __syncthreads();
        bf16x8 af[4], bf[4];
        #pragma unroll
        for (int m = 0; m < 4; ++m)
            af[m] = *reinterpret_cast<const bf16x8*>(&As[(wr * 64 + m * 16 + ln15) * 32 + kq * 8]);
        #pragma unroll
        for (int n = 0; n < 4; ++n)
            bf[n] = *reinterpret_cast<const bf16x8*>(&Bs[(wc * 64 + n * 16 + ln15) * 32 + kq * 8]);
        #pragma unroll
        for (int m = 0; m < 4; ++m)
            #pragma unroll
            for (int n = 0; n < 4; ++n)
                acc[m][n] = __builtin_amdgcn_mfma_f32_16x16x32_bf16(af[m], bf[n], acc[m][n], 0, 0, 0);
        __syncthreads();
    }
    #pragma unroll
    for (int m = 0; m < 4; ++m) {
        #pragma unroll
        for (int n = 0; n < 4; ++n) {
            int col = bn * 128 + wc * 64 + n * 16 + ln15;
            #pragma unroll
            for (int j = 0; j < 4; ++j) {
                int row = bm * 128 + wr * 64 + m * 16 + kq * 4 + j;
                if constexpr (OUT_BF16 != 0)
                    ((unsigned short*)C)[(size_t)row * N + col] = f2bf(acc[m][n][j]);
                else
                    ((float*)C)[(size_t)row * N + col] = acc[m][n][j];
            }
        }
    }
}

// ---------------- RoPE cos/sin table: [S][32] float2 ----------------
__global__ __launch_bounds__(256) void rope_table(const int* __restrict__ pos,
                                                  float2* __restrict__ tab) {
    int idx = blockIdx.x * 256 + threadIdx.x;  // s*32 + i
    int s = idx >> 5, i = idx & 31;
    float fpos = (float)pos[s];
    float freq = exp2f(-(float)i * (13.287712379549449f / 32.0f));  // theta^(-i/32)
    float ang = fpos * freq, sn, cs;
    sincosf(ang, &sn, &cs);
    tab[idx] = make_float2(cs, sn);
}

// ---------------- RoPE + split qkv[B*S][3072] -> Qh,Kh [B,H,S,64] ----------------
__global__ __launch_bounds__(256) void rope_kernel(
    const unsigned short* __restrict__ qkv, const float2* __restrict__ tab,
    unsigned short* __restrict__ Qh, unsigned short* __restrict__ Kh) {
    int bs = blockIdx.x;            // b*SEQ + s
    int b = bs >> 11, s = bs & (SEQ - 1);
    int t = threadIdx.x;
    #pragma unroll
    for (int p = t; p < 512; p += 256) {
        int h = p >> 5, i = p & 31;
        float2 cs = tab[(s << 5) + i];
        size_t src = (size_t)bs * 3072 + h * 64 + 2 * i;
        size_t dst = ((size_t)(b * NH + h) * SEQ + s) * 64 + 2 * i;
        ushort2 qv = *reinterpret_cast<const ushort2*>(qkv + src);
        float q0 = bf2f(qv.x), q1 = bf2f(qv.y);
        ushort2 qo;
        qo.x = f2bf((q0 * cs.x - q1 * cs.y) * QSCALE);
        qo.y = f2bf((q1 * cs.x + q0 * cs.y) * QSCALE);
        *reinterpret_cast<ushort2*>(Qh + dst) = qo;
        ushort2 kv = *reinterpret_cast<const ushort2*>(qkv + src + 1024);
        float k0 = bf2f(kv.x), k1 = bf2f(kv.y);
        ushort2 ko;
        ko.x = f2bf(k0 * cs.x - k1 * cs.y);
        ko.y = f2bf(k1 * cs.x + k0 * cs.y);
        *reinterpret_cast<ushort2*>(Kh + dst) = ko;
    }
}

// ---------------- V: qkv cols 2048.. -> [B,H,64,S] (tiled transpose) ----------------
__global__ __launch_bounds__(256) void vtrans_kernel(
    const unsigned short* __restrict__ qkv, unsigned short* __restrict__ Vo) {
    __shared__ unsigned short tile[64][65];
    int blk = blockIdx.x;           // (b*NH + h)*32 + st
    int st = blk & 31, bh = blk >> 5;
    int sb = st * 64;
    int t = threadIdx.x;
    int b = bh >> 4, h = bh & 15;
    #pragma unroll
    for (int u = t; u < 1024; u += 256) {
        int sl = u >> 4, d4 = (u & 15) << 2;
        ushort4 v = *reinterpret_cast<const ushort4*>(
            qkv + (size_t)(b * SEQ + sb + sl) * 3072 + 2048 + h * 64 + d4);
        tile[sl][d4] = v.x; tile[sl][d4 + 1] = v.y;
        tile[sl][d4 + 2] = v.z; tile[sl][d4 + 3] = v.w;
    }
    __syncthreads();
    #pragma unroll
    for (int u = t; u < 1024; u += 256) {
        int d = u >> 4, s4 = (u & 15) << 2;
        ushort4 o;
        o.x = tile[s4][d]; o.y = tile[s4 + 1][d];
        o.z = tile[s4 + 2][d]; o.w = tile[s4 + 3][d];
        *reinterpret_cast<ushort4*>(Vo + ((size_t)bh * 64 + d) * SEQ + sb + s4) = o;
    }
}

// ---------------- causal flash attention, barrier-free, reg double-buffered ----
// 4 independent waves/block (16 q-rows each). K,V read direct from global (L2-
// resident: 512 KB per (b,h)) into registers with one-tile explicit lookahead.
// LDS only for the per-wave private P transpose. No s_barrier anywhere.
__global__ __launch_bounds__(256) void attn_kernel(
    const unsigned short* __restrict__ Qh, const unsigned short* __restrict__ Kh,
    const unsigned short* __restrict__ Vt, unsigned short* __restrict__ Out) {
    __shared__ unsigned short Plds[4][16 * 40];

    const int tid = threadIdx.x;
    const int wid = tid >> 6, lane = tid & 63;
    const int ln15 = lane & 15, g = lane >> 4;
    const int bid = blockIdx.x;
    const int bh = bid & 31;
    const int band = 31 - (bid >> 5);           // longest-work-first
    const int qb = band * 64 + wid * 16;
    const int kend = qb + 15;
    const int nt = 2 * band + 2;                // 32-wide k-tiles (always even)

    const unsigned short* Qp = Qh + (size_t)bh * SEQ * 64;
    const unsigned short* Kp = Kh + (size_t)bh * SEQ * 64;
    const unsigned short* Vp = Vt + (size_t)bh * 64 * SEQ;
    unsigned short* P = Plds[wid];

    bf16x8 aq0 = *reinterpret_cast<const bf16x8*>(Qp + (size_t)(qb + ln15) * 64 + g * 8);
    bf16x8 aq1 = *reinterpret_cast<const bf16x8*>(Qp + (size_t)(qb + ln15) * 64 + 32 + g * 8);

    f32x4 oacc[4] = {};
    float lsum[4] = {0.f, 0.f, 0.f, 0.f};

    auto loadK = [&](int kb, bf16x8* k) {
        k[0] = *reinterpret_cast<const bf16x8*>(Kp + (size_t)(kb + ln15) * 64 + g * 8);
        k[1] = *reinterpret_cast<const bf16x8*>(Kp + (size_t)(kb + ln15) * 64 + 32 + g * 8);
        k[2] = *reinterpret_cast<const bf16x8*>(Kp + (size_t)(kb + 16 + ln15) * 64 + g * 8);
        k[3] = *reinterpret_cast<const bf16x8*>(Kp + (size_t)(kb + 16 + ln15) * 64 + 32 + g * 8);
    };
    auto loadV = [&](int kb, bf16x8* v) {
        #pragma unroll
        for (int c = 0; c < 4; ++c)
            v[c] = *reinterpret_cast<const bf16x8*>(
                Vp + (size_t)(c * 16 + ln15) * SEQ + kb + g * 8);
    };
    auto compute = [&](int kb, const bf16x8* k, const bf16x8* v) {
        if (kb > kend) return;
        const f32x4 z = {};
        f32x4 s0, s1;
        s0 = __builtin_amdgcn_mfma_f32_16x16x32_bf16(aq0, k[0], z, 0, 0, 0);
        s0 = __builtin_amdgcn_mfma_f32_16x16x32_bf16(aq1, k[1], s0, 0, 0, 0);
        s1 = __builtin_amdgcn_mfma_f32_16x16x32_bf16(aq0, k[2], z, 0, 0, 0);
        s1 = __builtin_amdgcn_mfma_f32_16x16x32_bf16(aq1, k[3], s1, 0, 0, 0);

        // Tile fully causal only if max k (kb+31) <= wave's MIN q-row (qb).
        const bool masked = (kb + 31) > qb;
        #pragma unroll
        for (int j = 0; j < 4; ++j) {
            float v0 = EXP2(s0[j]);
            float v1 = EXP2(s1[j]);
            if (masked) {
                int qg = qb + g * 4 + j;
                if (kb + ln15 > qg) v0 = 0.f;
                if (kb + 16 + ln15 > qg) v1 = 0.f;
            }
            lsum[j] += v0 + v1;
            P[(g * 4 + j) * 40 + ln15] = f2bf(v0);
            P[(g * 4 + j) * 40 + 16 + ln15] = f2bf(v1);
        }
        asm volatile("s_waitcnt lgkmcnt(0)" ::: "memory");
        bf16x8 ap = *reinterpret_cast<const bf16x8*>(&P[ln15 * 40 + g * 8]);
        #pragma unroll
        for (int c = 0; c < 4; ++c)
            oacc[c] = __builtin_amdgcn_mfma_f32_16x16x32_bf16(ap, v[c], oacc[c], 0, 0, 0);
        asm volatile("s_waitcnt lgkmcnt(0)" ::: "memory");  // P reads done before next overwrite
    };

    bf16x8 kA[4], vA[4], kB[4], vB[4];
    loadK(0, kA); loadV(0, vA);
    for (int t = 0; t < nt; t += 2) {
        // prefetch tile t+1 into B, compute tile t from A
        loadK((t + 1) << 5, kB); loadV((t + 1) << 5, vB);
        compute(t << 5, kA, vA);
        // prefetch tile t+2 (clamped) into A, compute tile t+1 from B
        int t2 = (t + 2 < nt) ? (t + 2) : (nt - 1);
        loadK(t2 << 5, kA); loadV(t2 << 5, vA);
        compute((t + 1) << 5, kB, vB);
    }

    float inv[4];
    #pragma unroll
    for (int j = 0; j < 4; ++j) {
        float r = lsum[j];
        #pragma unroll
        for (int off = 1; off < 16; off <<= 1)
            r += __shfl_xor(r, off);
        inv[j] = 1.f / r;
    }
    int b = bh >> 4, h = bh & 15;
    #pragma unroll
    for (int c = 0; c < 4; ++c)
        #pragma unroll
        for (int j = 0; j < 4; ++j) {
            int s = qb + g * 4 + j;
            Out[((size_t)(b * SEQ + s)) * DM + h * 64 + c * 16 + ln15] =
                f2bf(oacc[c][j] * inv[j]);
        }
}

extern "C" void kernel_launch(void* const* d_in, const int* in_sizes, int n_in,
                              void* d_out, int out_size, void* d_ws, size_t ws_size,
                              hipStream_t stream) {
    const float* x = (const float*)d_in[0];
    const int* pos = (const int*)d_in[1];
    const float* Wq = (const float*)d_in[2];
    const float* Wk = (const float*)d_in[3];
    const float* Wv = (const float*)d_in[4];
    const float* Wo = (const float*)d_in[5];
    float* out = (float*)d_out;

    char* ws = (char*)d_ws;
    const size_t MB = 1024 * 1024;
    unsigned short* xb   = (unsigned short*)(ws + 0 * MB);
    unsigned short* wqkv = (unsigned short*)(ws + 8 * MB);   // wq|wk|wv contiguous
    unsigned short* wob  = (unsigned short*)(ws + 14 * MB);
    unsigned short* qkv  = (unsigned short*)(ws + 16 * MB);  // [4096][3072]
    float2*         tab  = (float2*)       (ws + 40 * MB);   // [2048][32]
    unsigned short* qh   = (unsigned short*)(ws + 41 * MB);
    unsigned short* kh   = (unsigned short*)(ws + 49 * MB);
    unsigned short* vtr  = (unsigned short*)(ws + 57 * MB);
    unsigned short* att  = (unsigned short*)(ws + 65 * MB);

    cvt_all<<<8192, 256, 0, stream>>>(x, Wq, Wk, Wv, Wo, xb, wqkv, wob);
    rope_table<<<256, 256, 0, stream>>>(pos, tab);

    gemm_bt<1><<<dim3(24, 32), 256, 0, stream>>>(xb, wqkv, qkv, 4096, 3072, 1024);

    rope_kernel<<<4096, 256, 0, stream>>>(qkv, tab, qh, kh);
    vtrans_kernel<<<1024, 256, 0, stream>>>(qkv, vtr);

    attn_kernel<<<1024, 256, 0, stream>>>(qh, kh, vtr, att);

    gemm_bt<0><<<dim3(8, 32), 256, 0, stream>>>(att, wob, out, 4096, 1024, 1024);
}

// Round 6
// 132.993 us; speedup vs baseline: 1.6590x; 1.6590x over previous
//
#include <hip/hip_runtime.h>
#include <hip/hip_bf16.h>
#include <cstdint>
#include <cmath>

#define SEQ 2048
#define NH 16
#define DM 1024
#define BATCH 2

typedef short bf16x8 __attribute__((ext_vector_type(8)));
typedef float f32x4 __attribute__((ext_vector_type(4)));
typedef const void __attribute__((address_space(1)))* gas_t;
typedef void __attribute__((address_space(3)))* las_t;

#if __has_builtin(__builtin_amdgcn_exp2f)
#define EXP2(x) __builtin_amdgcn_exp2f(x)
#else
#define EXP2(x) __expf((x) * 0.6931471805599453f)
#endif

// Q prescale: (1/sqrt(64)) * log2(e) so scores are already in log2 domain
#define QSCALE 0.18033688011112042f

static __device__ __forceinline__ unsigned short f2bf(float f) {
    union { __hip_bfloat16 h; unsigned short u; } cv;
    cv.h = __float2bfloat16(f);
    return cv.u;
}
static __device__ __forceinline__ float bf2f(unsigned short u) {
    union { unsigned short u; __hip_bfloat16 h; } cv;
    cv.u = u;
    return __bfloat162float(cv.h);
}

static __device__ __forceinline__ void gload_lds16(const void* g, void* l) {
    __builtin_amdgcn_global_load_lds(
        reinterpret_cast<gas_t>(reinterpret_cast<uintptr_t>(g)),
        reinterpret_cast<las_t>(reinterpret_cast<uintptr_t>(l)),
        16, 0, 0);
}

// ---------------- fp32 -> bf16 convert, all 5 tensors in one launch ----------
__global__ __launch_bounds__(256) void cvt_all(
    const float* __restrict__ x,  const float* __restrict__ wq,
    const float* __restrict__ wk, const float* __restrict__ wv,
    const float* __restrict__ wo,
    unsigned short* __restrict__ xb, unsigned short* __restrict__ wqkv,
    unsigned short* __restrict__ wob) {
    int blk = blockIdx.x;
    const float* src; unsigned short* dst; int base;
    if (blk < 4096)      { src = x;  dst = xb;              base = blk; }
    else if (blk < 5120) { src = wq; dst = wqkv;            base = blk - 4096; }
    else if (blk < 6144) { src = wk; dst = wqkv + 1048576;  base = blk - 5120; }
    else if (blk < 7168) { src = wv; dst = wqkv + 2097152;  base = blk - 6144; }
    else                 { src = wo; dst = wob;             base = blk - 7168; }
    int i = base * 256 + threadIdx.x;
    float4 v = reinterpret_cast<const float4*>(src)[i];
    ushort4 o;
    o.x = f2bf(v.x); o.y = f2bf(v.y); o.z = f2bf(v.z); o.w = f2bf(v.w);
    reinterpret_cast<ushort4*>(dst)[i] = o;
}

// ---------------- bf16 GEMM: C[M][N] = A[M][K] * B[N][K]^T ----------------
template<int OUT_BF16>
__global__ __launch_bounds__(256) void gemm_bt(
    const unsigned short* __restrict__ A,
    const unsigned short* __restrict__ B,
    void* __restrict__ C, int M, int N, int K) {
    __shared__ unsigned short As[128 * 32];
    __shared__ unsigned short Bs[128 * 32];
    const int tid = threadIdx.x;
    const int lane = tid & 63, wid = tid >> 6;
    const int wr = wid >> 1, wc = wid & 1;
    const int ln15 = lane & 15, kq = lane >> 4;
    const int bm = blockIdx.y, bn = blockIdx.x;

    f32x4 acc[4][4] = {};
    const int nk = K >> 5;
    for (int kt = 0; kt < nk; ++kt) {
        #pragma unroll
        for (int i = 0; i < 2; ++i) {
            int c = i * 256 + tid;
            int row = c >> 2, k8 = (c & 3) << 3;
            size_t gofsA = (size_t)(bm * 128 + row) * K + kt * 32 + k8;
            size_t gofsB = (size_t)(bn * 128 + row) * K + kt * 32 + k8;
            unsigned ldsoff = (unsigned)(i * 256 + wid * 64) * 16;  // wave-uniform
            gload_lds16(A + gofsA, (char*)As + ldsoff);
            gload_lds16(B + gofsB, (char*)Bs + ldsoff);
        }
        __syncthreads();
        bf16x8 af[4], bf[4];
        #pragma unroll
        for (int m = 0; m < 4; ++m)
            af[m] = *reinterpret_cast<const bf16x8*>(&As[(wr * 64 + m * 16 + ln15) * 32 + kq * 8]);
        #pragma unroll
        for (int n = 0; n < 4; ++n)
            bf[n] = *reinterpret_cast<const bf16x8*>(&Bs[(wc * 64 + n * 16 + ln15) * 32 + kq * 8]);
        #pragma unroll
        for (int m = 0; m < 4; ++m)
            #pragma unroll
            for (int n = 0; n < 4; ++n)
                acc[m][n] = __builtin_amdgcn_mfma_f32_16x16x32_bf16(af[m], bf[n], acc[m][n], 0, 0, 0);
        __syncthreads();
    }
    #pragma unroll
    for (int m = 0; m < 4; ++m) {
        #pragma unroll
        for (int n = 0; n < 4; ++n) {
            int col = bn * 128 + wc * 64 + n * 16 + ln15;
            #pragma unroll
            for (int j = 0; j < 4; ++j) {
                int row = bm * 128 + wr * 64 + m * 16 + kq * 4 + j;
                if constexpr (OUT_BF16 != 0)
                    ((unsigned short*)C)[(size_t)row * N + col] = f2bf(acc[m][n][j]);
                else
                    ((float*)C)[(size_t)row * N + col] = acc[m][n][j];
            }
        }
    }
}

// ---------------- RoPE cos/sin table: [S][32] float2 ----------------
__global__ __launch_bounds__(256) void rope_table(const int* __restrict__ pos,
                                                  float2* __restrict__ tab) {
    int idx = blockIdx.x * 256 + threadIdx.x;  // s*32 + i
    int s = idx >> 5, i = idx & 31;
    float fpos = (float)pos[s];
    float freq = exp2f(-(float)i * (13.287712379549449f / 32.0f));  // theta^(-i/32)
    float ang = fpos * freq, sn, cs;
    sincosf(ang, &sn, &cs);
    tab[idx] = make_float2(cs, sn);
}

// ---------------- RoPE + split qkv[B*S][3072] -> Qh,Kh [B,H,S,64] ----------------
__global__ __launch_bounds__(256) void rope_kernel(
    const unsigned short* __restrict__ qkv, const float2* __restrict__ tab,
    unsigned short* __restrict__ Qh, unsigned short* __restrict__ Kh) {
    int bs = blockIdx.x;            // b*SEQ + s
    int b = bs >> 11, s = bs & (SEQ - 1);
    int t = threadIdx.x;
    #pragma unroll
    for (int p = t; p < 512; p += 256) {
        int h = p >> 5, i = p & 31;
        float2 cs = tab[(s << 5) + i];
        size_t src = (size_t)bs * 3072 + h * 64 + 2 * i;
        size_t dst = ((size_t)(b * NH + h) * SEQ + s) * 64 + 2 * i;
        ushort2 qv = *reinterpret_cast<const ushort2*>(qkv + src);
        float q0 = bf2f(qv.x), q1 = bf2f(qv.y);
        ushort2 qo;
        qo.x = f2bf((q0 * cs.x - q1 * cs.y) * QSCALE);
        qo.y = f2bf((q1 * cs.x + q0 * cs.y) * QSCALE);
        *reinterpret_cast<ushort2*>(Qh + dst) = qo;
        ushort2 kv = *reinterpret_cast<const ushort2*>(qkv + src + 1024);
        float k0 = bf2f(kv.x), k1 = bf2f(kv.y);
        ushort2 ko;
        ko.x = f2bf(k0 * cs.x - k1 * cs.y);
        ko.y = f2bf(k1 * cs.x + k0 * cs.y);
        *reinterpret_cast<ushort2*>(Kh + dst) = ko;
    }
}

// ---------------- V: qkv cols 2048.. -> [B,H,64,S] (tiled transpose) ----------------
__global__ __launch_bounds__(256) void vtrans_kernel(
    const unsigned short* __restrict__ qkv, unsigned short* __restrict__ Vo) {
    __shared__ unsigned short tile[64][65];
    int blk = blockIdx.x;           // (b*NH + h)*32 + st
    int st = blk & 31, bh = blk >> 5;
    int sb = st * 64;
    int t = threadIdx.x;
    int b = bh >> 4, h = bh & 15;
    #pragma unroll
    for (int u = t; u < 1024; u += 256) {
        int sl = u >> 4, d4 = (u & 15) << 2;
        ushort4 v = *reinterpret_cast<const ushort4*>(
            qkv + (size_t)(b * SEQ + sb + sl) * 3072 + 2048 + h * 64 + d4);
        tile[sl][d4] = v.x; tile[sl][d4 + 1] = v.y;
        tile[sl][d4 + 2] = v.z; tile[sl][d4 + 3] = v.w;
    }
    __syncthreads();
    #pragma unroll
    for (int u = t; u < 1024; u += 256) {
        int d = u >> 4, s4 = (u & 15) << 2;
        ushort4 o;
        o.x = tile[s4][d]; o.y = tile[s4 + 1][d];
        o.z = tile[s4 + 2][d]; o.w = tile[s4 + 3][d];
        *reinterpret_cast<ushort4*>(Vo + ((size_t)bh * 64 + d) * SEQ + sb + s4) = o;
    }
}

// ---------------- causal flash attention, LDS-staged K/V, swapped QK^T --------
// 2 waves/block, band of 32 q rows (16/wave). K-tile 32x64 + Vt-tile 64x32
// staged via global_load_lds (linear dest, inverse-swizzled source), double-
// buffered with counted vmcnt. Swapped QK^T (mfma(K,Q)) puts a full q-row's
// scores on one lane: scalar lsum, 2 packed P stores/tile, mask only last tile.
__global__ __launch_bounds__(128) void attn_kernel(
    const unsigned short* __restrict__ Qh, const unsigned short* __restrict__ Kh,
    const unsigned short* __restrict__ Vt, unsigned short* __restrict__ Out) {
    __shared__ unsigned short Kb[2][32 * 64];   // [k][d], slot-swizzled
    __shared__ unsigned short Vb[2][64 * 32];   // [d][k], slot-swizzled
    __shared__ unsigned short Plds[2][16 * 40];

    const int tid = threadIdx.x;
    const int wid = tid >> 6, lane = tid & 63;
    const int ln15 = lane & 15, g = lane >> 4;
    const int bid = blockIdx.x;
    const int bh = bid & 31;
    const int band = 63 - (bid >> 5);           // longest-work-first, 32 q rows
    const int qb = band * 32 + wid * 16;
    const int nt = band + 1;                    // 32-wide k-tiles for this block

    const unsigned short* Qp = Qh + (size_t)bh * SEQ * 64;
    const unsigned short* Kp = Kh + (size_t)bh * SEQ * 64;
    const unsigned short* Vp = Vt + (size_t)bh * 64 * SEQ;
    unsigned short* P = Plds[wid];

    // --- staging: 256 chunks x 16B per tile, 128 threads -> 2 chunks each ---
    // K: chunk c -> row k=c>>3, slot=c&7 holds d-block (slot ^ (k&7))
    const int c0 = tid, c1 = tid + 128;
    const unsigned short* kSrc0 = Kp + (size_t)(c0 >> 3) * 64 + (((c0 & 7) ^ ((c0 >> 3) & 7)) << 3);
    const unsigned short* kSrc1 = Kp + (size_t)(c1 >> 3) * 64 + (((c1 & 7) ^ ((c1 >> 3) & 7)) << 3);
    // V: chunk c -> row d=c>>2, slot=c&3 holds k-block (slot ^ ((d>>1)&3))
    const unsigned short* vSrc0 = Vp + (size_t)(c0 >> 2) * SEQ + (((c0 & 3) ^ (((c0 >> 2) >> 1) & 3)) << 3);
    const unsigned short* vSrc1 = Vp + (size_t)(c1 >> 2) * SEQ + (((c1 & 3) ^ (((c1 >> 2) >> 1) & 3)) << 3);
    const unsigned base0 = (unsigned)wid * 1024;          // chunks 0..127
    const unsigned base1 = 2048 + (unsigned)wid * 1024;   // chunks 128..255

    auto stage = [&](int kb, int buf) {
        gload_lds16(kSrc0 + (size_t)kb * 64, (char*)Kb[buf] + base0);
        gload_lds16(kSrc1 + (size_t)kb * 64, (char*)Kb[buf] + base1);
        gload_lds16(vSrc0 + kb, (char*)Vb[buf] + base0);
        gload_lds16(vSrc1 + kb, (char*)Vb[buf] + base1);
    };

    // --- compute-side LDS byte offsets (fixed per lane) ---
    const int r0 = ln15, r1 = ln15 + 16;
    const unsigned kOff0a = r0 * 128 + ((g ^ (r0 & 7)) << 4);
    const unsigned kOff0b = r0 * 128 + (((4 + g) ^ (r0 & 7)) << 4);
    const unsigned kOff1a = r1 * 128 + ((g ^ (r1 & 7)) << 4);
    const unsigned kOff1b = r1 * 128 + (((4 + g) ^ (r1 & 7)) << 4);
    unsigned vOff[4];
    #pragma unroll
    for (int c = 0; c < 4; ++c) {
        int d = c * 16 + ln15;
        vOff[c] = d * 64 + ((g ^ ((d >> 1) & 3)) << 4);
    }

    bf16x8 aq0 = *reinterpret_cast<const bf16x8*>(Qp + (size_t)(qb + ln15) * 64 + g * 8);
    bf16x8 aq1 = *reinterpret_cast<const bf16x8*>(Qp + (size_t)(qb + ln15) * 64 + 32 + g * 8);

    f32x4 oacc[4] = {};
    float lsum = 0.f;
    const int thr = qb + ln15 - 4 * g;   // allowed: kb + 4g + j <= qb + ln15

    stage(0, 0);   // prologue

    for (int t = 0; t < nt; ++t) {
        const int kb = t << 5;
        const int cur = t & 1, nxt = cur ^ 1;
        {
            int tn = t + 1; if (tn > nt - 1) tn = nt - 1;   // clamped re-stage
            stage(tn << 5, nxt);
        }
        asm volatile("s_waitcnt vmcnt(4)" ::: "memory");   // tile t's 4 loads done
        __builtin_amdgcn_s_barrier();

        const unsigned short* K0 = Kb[cur];
        const unsigned short* V0 = Vb[cur];
        const f32x4 z = {};
        // swapped: A = K-frag (rows = k), B = Q-frag (cols = q). Lane holds
        // scores for q = qb+ln15, k = kb + 4g+j (s0) / kb+16+4g+j (s1).
        bf16x8 kf0 = *reinterpret_cast<const bf16x8*>((const char*)K0 + kOff0a);
        bf16x8 kf1 = *reinterpret_cast<const bf16x8*>((const char*)K0 + kOff0b);
        bf16x8 kf2 = *reinterpret_cast<const bf16x8*>((const char*)K0 + kOff1a);
        bf16x8 kf3 = *reinterpret_cast<const bf16x8*>((const char*)K0 + kOff1b);
        f32x4 s0, s1;
        s0 = __builtin_amdgcn_mfma_f32_16x16x32_bf16(kf0, aq0, z, 0, 0, 0);
        s0 = __builtin_amdgcn_mfma_f32_16x16x32_bf16(kf1, aq1, s0, 0, 0, 0);
        s1 = __builtin_amdgcn_mfma_f32_16x16x32_bf16(kf2, aq0, z, 0, 0, 0);
        s1 = __builtin_amdgcn_mfma_f32_16x16x32_bf16(kf3, aq1, s1, 0, 0, 0);

        float p0[4], p1[4];
        if (t == band) {     // only the boundary tile needs the causal mask
            #pragma unroll
            for (int j = 0; j < 4; ++j) {
                p0[j] = (j <= thr - kb) ? EXP2(s0[j]) : 0.f;
                p1[j] = (j <= thr - kb - 16) ? EXP2(s1[j]) : 0.f;
            }
        } else {
            #pragma unroll
            for (int j = 0; j < 4; ++j) { p0[j] = EXP2(s0[j]); p1[j] = EXP2(s1[j]); }
        }
        lsum += (p0[0] + p0[1]) + (p0[2] + p0[3]) + (p1[0] + p1[1]) + (p1[2] + p1[3]);

        ushort4 w0, w1;
        w0.x = f2bf(p0[0]); w0.y = f2bf(p0[1]); w0.z = f2bf(p0[2]); w0.w = f2bf(p0[3]);
        w1.x = f2bf(p1[0]); w1.y = f2bf(p1[1]); w1.z = f2bf(p1[2]); w1.w = f2bf(p1[3]);
        *reinterpret_cast<ushort4*>(&P[ln15 * 40 + 4 * g]) = w0;        // k-local 4g..4g+3
        *reinterpret_cast<ushort4*>(&P[ln15 * 40 + 16 + 4 * g]) = w1;   // k-local 16+4g..
        asm volatile("s_waitcnt lgkmcnt(0)" ::: "memory");
        bf16x8 ap = *reinterpret_cast<const bf16x8*>(&P[ln15 * 40 + 8 * g]);
        #pragma unroll
        for (int c = 0; c < 4; ++c) {
            bf16x8 bv = *reinterpret_cast<const bf16x8*>((const char*)V0 + vOff[c]);
            oacc[c] = __builtin_amdgcn_mfma_f32_16x16x32_bf16(ap, bv, oacc[c], 0, 0, 0);
        }
        asm volatile("s_waitcnt lgkmcnt(0)" ::: "memory");  // K/V reads of cur done
        __builtin_amdgcn_s_barrier();
    }

    // row sum lives split across the 4 g-lanes of each ln15: reduce, invert,
    // then redistribute to the (g,j) layout of the O accumulator rows.
    float r = lsum;
    r += __shfl_xor(r, 16);
    r += __shfl_xor(r, 32);
    float linv = 1.f / r;
    float invj[4];
    #pragma unroll
    for (int j = 0; j < 4; ++j)
        invj[j] = __shfl(linv, 20 * g + j);   // lane with ln15 == 4g+j

    int b = bh >> 4, h = bh & 15;
    #pragma unroll
    for (int c = 0; c < 4; ++c)
        #pragma unroll
        for (int j = 0; j < 4; ++j) {
            int s = qb + g * 4 + j;
            Out[((size_t)(b * SEQ + s)) * DM + h * 64 + c * 16 + ln15] =
                f2bf(oacc[c][j] * invj[j]);
        }
}

extern "C" void kernel_launch(void* const* d_in, const int* in_sizes, int n_in,
                              void* d_out, int out_size, void* d_ws, size_t ws_size,
                              hipStream_t stream) {
    const float* x = (const float*)d_in[0];
    const int* pos = (const int*)d_in[1];
    const float* Wq = (const float*)d_in[2];
    const float* Wk = (const float*)d_in[3];
    const float* Wv = (const float*)d_in[4];
    const float* Wo = (const float*)d_in[5];
    float* out = (float*)d_out;

    char* ws = (char*)d_ws;
    const size_t MB = 1024 * 1024;
    unsigned short* xb   = (unsigned short*)(ws + 0 * MB);
    unsigned short* wqkv = (unsigned short*)(ws + 8 * MB);   // wq|wk|wv contiguous
    unsigned short* wob  = (unsigned short*)(ws + 14 * MB);
    unsigned short* qkv  = (unsigned short*)(ws + 16 * MB);  // [4096][3072]
    float2*         tab  = (float2*)       (ws + 40 * MB);   // [2048][32]
    unsigned short* qh   = (unsigned short*)(ws + 41 * MB);
    unsigned short* kh   = (unsigned short*)(ws + 49 * MB);
    unsigned short* vtr  = (unsigned short*)(ws + 57 * MB);
    unsigned short* att  = (unsigned short*)(ws + 65 * MB);

    cvt_all<<<8192, 256, 0, stream>>>(x, Wq, Wk, Wv, Wo, xb, wqkv, wob);
    rope_table<<<256, 256, 0, stream>>>(pos, tab);

    gemm_bt<1><<<dim3(24, 32), 256, 0, stream>>>(xb, wqkv, qkv, 4096, 3072, 1024);

    rope_kernel<<<4096, 256, 0, stream>>>(qkv, tab, qh, kh);
    vtrans_kernel<<<1024, 256, 0, stream>>>(qkv, vtr);

    attn_kernel<<<2048, 128, 0, stream>>>(qh, kh, vtr, att);

    gemm_bt<0><<<dim3(8, 32), 256, 0, stream>>>(att, wob, out, 4096, 1024, 1024);
}